// Round 12
// baseline (90.287 us; speedup 1.0000x reference)
//
#include <hip/hip_runtime.h>
#include <hip/hip_bf16.h>

#define DDIM   256   // K (feature dim)
#define BROWS  256   // block output rows (4 waves x 64 rows)
#define BCOLS   32   // B tile columns
#define NTILES   8   // B tiles per block -> 256 cols per chunk

typedef float f32x4 __attribute__((ext_vector_type(4)));

// pack 4 f32 -> 4 fp8 e4m3 bytes
__device__ __forceinline__ unsigned int pack4_fp8(float a0, float a1, float a2, float a3) {
  int v = __builtin_amdgcn_cvt_pk_fp8_f32(a0, a1, 0, false);   // bytes 0,1
  v = __builtin_amdgcn_cvt_pk_fp8_f32(a2, a3, v, true);        // bytes 2,3
  return (unsigned int)v;
}

// ---- prep: one wave per row; writes UNIT-NORM fp8 rows + exact f32 diag ----
__global__ __launch_bounds__(256) void prep_kernel(
    const float* __restrict__ q, const float* __restrict__ r,
    unsigned char* __restrict__ qf8, unsigned char* __restrict__ rf8,
    float* __restrict__ pos, float* __restrict__ row_sum) {
  int lane = threadIdx.x & 63, wave = threadIdx.x >> 6;
  int row = blockIdx.x * 4 + wave;
  size_t base = (size_t)row * DDIM + lane * 4;
  float4 qv = *(const float4*)(q + base);
  float4 rv = *(const float4*)(r + base);
  float qq = qv.x*qv.x + qv.y*qv.y + qv.z*qv.z + qv.w*qv.w;
  float rr = rv.x*rv.x + rv.y*rv.y + rv.z*rv.z + rv.w*rv.w;
  float qr = qv.x*rv.x + qv.y*rv.y + qv.z*rv.z + qv.w*rv.w;
  #pragma unroll
  for (int m = 1; m < 64; m <<= 1) {
    qq += __shfl_xor(qq, m);
    rr += __shfl_xor(rr, m);
    qr += __shfl_xor(qr, m);
  }
  float iq = 1.0f / sqrtf(qq);
  float ir = 1.0f / sqrtf(rr);
  unsigned int qp = pack4_fp8(qv.x*iq, qv.y*iq, qv.z*iq, qv.w*iq);
  unsigned int rp = pack4_fp8(rv.x*ir, rv.y*ir, rv.z*ir, rv.w*ir);
  *(unsigned int*)(qf8 + base) = qp;
  *(unsigned int*)(rf8 + base) = rp;
  if (lane == 0) {
    pos[row] = qr * iq * ir;   // exact f32 diagonal from raw inputs
    row_sum[row] = 0.0f;
  }
}

// LDS-FREE GEMM+LSE. The MFMA B-fragment for (col, ks, g) is the contiguous
// 8 bytes R[col][ks*32+g*8 .. +8] — load it straight global->register.
// An 8 KB B tile is shared by all waves of all co-resident blocks -> L1/L2
// resident. No LDS, no barriers, no bank conflicts: each wave is an
// independent pipeline; next-tile loads overlap current-tile MFMA (the
// compiler places s_waitcnt before first USE of the prefetched regs).
__device__ __forceinline__ void load_btile(long (&bv)[16], const char* Rb,
                                           int col0, int g, int c) {
  const char* base = Rb + (size_t)(col0 + c) * 256 + g * 8;
  #pragma unroll
  for (int h = 0; h < 2; ++h)
    #pragma unroll
    for (int ks = 0; ks < 8; ++ks)
      bv[h * 8 + ks] = *(const long*)(base + h * 16 * 256 + ks * 32);
}

__device__ __forceinline__ void compute_btile(const long (&bv)[16],
                                              const long (&av)[4][8],
                                              float (&rs)[16]) {
  f32x4 acc[4][2];
  const f32x4 zero = {0.f, 0.f, 0.f, 0.f};
  #pragma unroll
  for (int m = 0; m < 4; ++m) { acc[m][0] = zero; acc[m][1] = zero; }

  #pragma unroll
  for (int ks = 0; ks < 8; ++ks) {
    #pragma unroll
    for (int m = 0; m < 4; ++m) {
      acc[m][0] = __builtin_amdgcn_mfma_f32_16x16x32_fp8_fp8(av[m][ks], bv[ks],     acc[m][0], 0, 0, 0);
      acc[m][1] = __builtin_amdgcn_mfma_f32_16x16x32_fp8_fp8(av[m][ks], bv[8 + ks], acc[m][1], 0, 0, 0);
    }
  }

  // unit-norm inputs: score = acc. C layout: col = h*16+c, row = m*16+g*4+jj
  #pragma unroll
  for (int m = 0; m < 4; ++m)
    #pragma unroll
    for (int jj = 0; jj < 4; ++jj)
      rs[m * 4 + jj] += __expf(acc[m][0][jj]) + __expf(acc[m][1][jj]);
}

// 256 threads = 4 waves x 64 rows. (256,2) gives the 256-total-reg budget
// class (R9-verified): demand ~ av(64) + bv(2x32) + acc(32 AGPR) + rs(16)
// + misc ~ 185 -> 2-3 waves/SIMD, no spill. No __syncthreads anywhere in
// the loop — the 26-29% MfmaUtil plateau of R2-R11 was the 2-phase
// barrier-drain structure, not tile shape.
__global__ __launch_bounds__(256, 2) void gemm_lse_kernel(
    const unsigned char* __restrict__ qf8, const unsigned char* __restrict__ rf8,
    float* __restrict__ row_sum) {
  const int tid  = threadIdx.x;
  const int lane = tid & 63;
  const int wid  = tid >> 6;            // 4 waves, each owns 64 rows
  const int g = lane >> 4, c = lane & 15;
  const int row0  = blockIdx.x * BROWS;
  const int col00 = blockIdx.y * (NTILES * BCOLS);
  const char* Rb = (const char*)rf8;

  // A fragments -> registers (4 row-frags x 8 K-slices = 64 VGPR), read once
  long av[4][8];
  const char* Ab = (const char*)qf8;
  #pragma unroll
  for (int m = 0; m < 4; ++m) {
    size_t rb = (size_t)(row0 + wid * 64 + m * 16 + c) * 256;
    #pragma unroll
    for (int ks = 0; ks < 8; ++ks)
      av[m][ks] = *(const long*)(Ab + rb + ks * 32 + g * 8);
  }

  float rs[16];
  #pragma unroll
  for (int k = 0; k < 16; ++k) rs[k] = 0.0f;

  // register double-buffer pipeline over 8 B tiles; manual x2 unroll keeps
  // buffer names static (no dynamic indexing -> no scratch, rule #20)
  long bv0[16], bv1[16];
  load_btile(bv0, Rb, col00, g, c);
  for (int t = 0; t < NTILES; t += 2) {
    if (t + 1 < NTILES)
      load_btile(bv1, Rb, col00 + (t + 1) * BCOLS, g, c);
    compute_btile(bv0, av, rs);
    if (t + 2 < NTILES)
      load_btile(bv0, Rb, col00 + (t + 2) * BCOLS, g, c);
    compute_btile(bv1, av, rs);
  }

  // reduce the 16 column-lanes holding the same row, one atomic per row
  #pragma unroll
  for (int k = 0; k < 16; ++k) {
    float v = rs[k];
    v += __shfl_xor(v, 1);
    v += __shfl_xor(v, 2);
    v += __shfl_xor(v, 4);
    v += __shfl_xor(v, 8);
    if (c == 0) {
      int row = row0 + wid * 64 + (k >> 2) * 16 + g * 4 + (k & 3);
      atomicAdd(&row_sum[row], v);
    }
  }
}

__global__ __launch_bounds__(256) void finalize_kernel(
    const float* __restrict__ row_sum, const float* __restrict__ pos,
    float* __restrict__ out, int n) {
  int t = threadIdx.x;
  float s = 0.f;
  #pragma unroll 4
  for (int i = t; i < n; i += 256) s += __logf(row_sum[i]) - pos[i];
  #pragma unroll
  for (int m = 1; m < 64; m <<= 1) s += __shfl_xor(s, m);
  __shared__ float red[4];
  if ((t & 63) == 0) red[t >> 6] = s;
  __syncthreads();
  if (t == 0) out[0] = red[0] + red[1] + red[2] + red[3];  // -loss = sum(lse - pos)
}

extern "C" void kernel_launch(void* const* d_in, const int* in_sizes, int n_in,
                              void* d_out, int out_size, void* d_ws, size_t ws_size,
                              hipStream_t stream) {
  const float* q = (const float*)d_in[0];
  const float* r = (const float*)d_in[1];
  int n = in_sizes[0] / DDIM;  // 8192

  char* w = (char*)d_ws;
  size_t f8Bytes = (size_t)n * DDIM;
  unsigned char* qf8 = (unsigned char*)w;
  unsigned char* rf8 = (unsigned char*)(w + f8Bytes);
  float* pos     = (float*)(w + 2 * f8Bytes);
  float* row_sum = pos + n;

  prep_kernel<<<n / 4, 256, 0, stream>>>(q, r, qf8, rf8, pos, row_sum);

  dim3 grid(n / BROWS, n / (NTILES * BCOLS));   // 32 x 32 = 1024 blocks
  gemm_lse_kernel<<<grid, 256, 0, stream>>>(qf8, rf8, row_sum);

  finalize_kernel<<<1, 256, 0, stream>>>(row_sum, pos, (float*)d_out, n);
}

// Round 13
// 47.545 us; speedup vs baseline: 1.8990x; 1.8990x over previous
//
#include <hip/hip_runtime.h>
#include <hip/hip_bf16.h>

#define DDIM   256    // K (feature dim)
#define BROWS  256    // block output rows (4 waves x 64 rows)
#define BN      64    // cols per N-tile
#define NT       8    // N-tiles per block -> 512-col chunk
#define TS   (BN * DDIM)   // 16 KB per buffer

typedef float f32x4 __attribute__((ext_vector_type(4)));

// pack 4 f32 -> 4 fp8 e4m3 bytes
__device__ __forceinline__ unsigned int pack4_fp8(float a0, float a1, float a2, float a3) {
  int v = __builtin_amdgcn_cvt_pk_fp8_f32(a0, a1, 0, false);   // bytes 0,1
  v = __builtin_amdgcn_cvt_pk_fp8_f32(a2, a3, v, true);        // bytes 2,3
  return (unsigned int)v;
}

// ---- prep: one wave per row; writes UNIT-NORM fp8 rows + exact f32 diag ----
__global__ __launch_bounds__(256) void prep_kernel(
    const float* __restrict__ q, const float* __restrict__ r,
    unsigned char* __restrict__ qf8, unsigned char* __restrict__ rf8,
    float* __restrict__ pos, float* __restrict__ row_sum) {
  int lane = threadIdx.x & 63, wave = threadIdx.x >> 6;
  int row = blockIdx.x * 4 + wave;
  size_t base = (size_t)row * DDIM + lane * 4;
  float4 qv = *(const float4*)(q + base);
  float4 rv = *(const float4*)(r + base);
  float qq = qv.x*qv.x + qv.y*qv.y + qv.z*qv.z + qv.w*qv.w;
  float rr = rv.x*rv.x + rv.y*rv.y + rv.z*rv.z + rv.w*rv.w;
  float qr = qv.x*rv.x + qv.y*rv.y + qv.z*rv.z + qv.w*rv.w;
  #pragma unroll
  for (int m = 1; m < 64; m <<= 1) {
    qq += __shfl_xor(qq, m);
    rr += __shfl_xor(rr, m);
    qr += __shfl_xor(qr, m);
  }
  float iq = 1.0f / sqrtf(qq);
  float ir = 1.0f / sqrtf(rr);
  unsigned int qp = pack4_fp8(qv.x*iq, qv.y*iq, qv.z*iq, qv.w*iq);
  unsigned int rp = pack4_fp8(rv.x*ir, rv.y*ir, rv.z*ir, rv.w*ir);
  *(unsigned int*)(qf8 + base) = qp;
  *(unsigned int*)(rf8 + base) = rp;
  if (lane == 0) {
    pos[row] = qr * iq * ir;   // exact f32 diagonal from raw inputs
    row_sum[row] = 0.0f;
  }
}

// stage phase p (cols [p*16,(p+1)*16)) of a 64-col fp8 tile: 1 load/thread.
// LDS layout: byte(col, koff) = col*256 + (koff ^ ((col&15)<<4)).
// global_load_lds writes linearly, so the SOURCE is inverse-swizzled (rule 21).
__device__ __forceinline__ void stage_phase(char* dstBase,
                                            const unsigned char* src_base,
                                            int col0, int p, int tid) {
  int ch = p * 256 + tid;              // 16B-chunk id 0..1023
  int cc = ch >> 4;                    // tile-local col (p*16 .. p*16+15)
  int w  = (ch & 15) << 4;             // 16B block within the 256B row
  int src = cc * 256 + (w ^ ((cc & 15) << 4));
  __builtin_amdgcn_global_load_lds(
      (const __attribute__((address_space(1))) void*)((const char*)src_base + (size_t)col0 * 256 + src),
      (__attribute__((address_space(3))) void*)(dstBase + ch * 16),
      16, 0, 0);
}

// T3+T4 phase-scheduled GEMM+LSE: 3 LDS buffers, staged 2 tiles ahead,
// counted vmcnt(4) at tile boundaries (never 0 in steady state), per-phase
// barrier pairs clustering MFMA (T5 setprio arbitrates role-split waves).
__global__ __launch_bounds__(256, 2) void gemm_lse_kernel(
    const unsigned char* __restrict__ qf8, const unsigned char* __restrict__ rf8,
    float* __restrict__ row_sum) {
  __shared__ __attribute__((aligned(16))) unsigned char Bl[3 * TS];  // 48 KB

  const int tid  = threadIdx.x;
  const int lane = tid & 63;
  const int wid  = tid >> 6;            // 4 waves, each owns 64 rows
  const int g = lane >> 4, c = lane & 15;
  const int row0  = blockIdx.x * BROWS;
  const int col00 = blockIdx.y * (NT * BN);
  const unsigned char* Rb = rf8;

  // prologue: stage tiles 0 and 1 fully (8 loads/thread in flight)
  #pragma unroll
  for (int p = 0; p < 4; ++p) stage_phase((char*)Bl,      Rb, col00,      p, tid);
  #pragma unroll
  for (int p = 0; p < 4; ++p) stage_phase((char*)Bl + TS, Rb, col00 + BN, p, tid);

  // A fragments -> registers (4 row-frags x 8 K-slices = 64 VGPR), read once;
  // their L2 latency overlaps the staging in flight.
  long av[4][8];
  const char* Ab = (const char*)qf8;
  #pragma unroll
  for (int m = 0; m < 4; ++m) {
    size_t rb0 = (size_t)(row0 + wid * 64 + m * 16 + c) * 256;
    #pragma unroll
    for (int ks = 0; ks < 8; ++ks)
      av[m][ks] = *(const long*)(Ab + rb0 + ks * 32 + g * 8);
  }

  float rs[16];
  #pragma unroll
  for (int k = 0; k < 16; ++k) rs[k] = 0.0f;

  // tile 0 resident: 4 newest outstanding loads are tile 1's
  asm volatile("s_waitcnt vmcnt(4)" ::: "memory");
  __builtin_amdgcn_s_barrier();

  int rb = 0;            // read-buffer byte base (t % 3)
  int wb = 2 * TS;       // write-buffer byte base ((t+2) % 3)
  for (int t = 0; t < NT; ++t) {
    #pragma unroll
    for (int p = 0; p < 4; ++p) {
      // issue 1/4 of tile t+2's staging (this phase's col group)
      if (t + 2 < NT)
        stage_phase((char*)Bl + wb, Rb, col00 + (t + 2) * BN, p, tid);

      // ds_read this phase's 16-col B fragments (col = p*16 + c)
      const char* colp = (const char*)Bl + rb + (p * 16 + c) * 256;
      const int swz = c << 4;
      long bv[8];
      #pragma unroll
      for (int ks = 0; ks < 8; ++ks)
        bv[ks] = *(const long*)(colp + ((ks * 32 + g * 8) ^ swz));

      __builtin_amdgcn_s_barrier();   // align waves: loads issued, enter MFMA

      f32x4 acc[4];
      const f32x4 zero = {0.f, 0.f, 0.f, 0.f};
      #pragma unroll
      for (int m = 0; m < 4; ++m) acc[m] = zero;
      __builtin_amdgcn_s_setprio(1);
      #pragma unroll
      for (int ks = 0; ks < 8; ++ks)
        #pragma unroll
        for (int m = 0; m < 4; ++m)
          acc[m] = __builtin_amdgcn_mfma_f32_16x16x32_fp8_fp8(av[m][ks], bv[ks], acc[m], 0, 0, 0);
      __builtin_amdgcn_s_setprio(0);

      // unit-norm inputs: score = acc. C layout: col = p*16+c, row = m*16+g*4+jj
      #pragma unroll
      for (int m = 0; m < 4; ++m)
        #pragma unroll
        for (int jj = 0; jj < 4; ++jj)
          rs[m * 4 + jj] += __expf(acc[m][jj]);

      __builtin_amdgcn_s_barrier();   // all waves done with this phase
    }

    // tile boundary: wait until tile t+1 is fully resident, keeping the
    // 4 loads issued this tile (for t+2) in flight across the barrier.
    if (t + 2 < NT) asm volatile("s_waitcnt vmcnt(4)" ::: "memory");
    else            asm volatile("s_waitcnt vmcnt(0)" ::: "memory");
    __builtin_amdgcn_s_barrier();

    rb += TS; if (rb == 3 * TS) rb = 0;
    wb += TS; if (wb == 3 * TS) wb = 0;
  }

  // reduce the 16 column-lanes holding the same row, one atomic per row
  #pragma unroll
  for (int k = 0; k < 16; ++k) {
    float v = rs[k];
    v += __shfl_xor(v, 1);
    v += __shfl_xor(v, 2);
    v += __shfl_xor(v, 4);
    v += __shfl_xor(v, 8);
    if (c == 0) {
      int row = row0 + wid * 64 + (k >> 2) * 16 + g * 4 + (k & 3);
      atomicAdd(&row_sum[row], v);
    }
  }
}

__global__ __launch_bounds__(256) void finalize_kernel(
    const float* __restrict__ row_sum, const float* __restrict__ pos,
    float* __restrict__ out, int n) {
  int t = threadIdx.x;
  float s = 0.f;
  #pragma unroll 4
  for (int i = t; i < n; i += 256) s += __logf(row_sum[i]) - pos[i];
  #pragma unroll
  for (int m = 1; m < 64; m <<= 1) s += __shfl_xor(s, m);
  __shared__ float red[4];
  if ((t & 63) == 0) red[t >> 6] = s;
  __syncthreads();
  if (t == 0) out[0] = red[0] + red[1] + red[2] + red[3];  // -loss = sum(lse - pos)
}

extern "C" void kernel_launch(void* const* d_in, const int* in_sizes, int n_in,
                              void* d_out, int out_size, void* d_ws, size_t ws_size,
                              hipStream_t stream) {
  const float* q = (const float*)d_in[0];
  const float* r = (const float*)d_in[1];
  int n = in_sizes[0] / DDIM;  // 8192

  char* w = (char*)d_ws;
  size_t f8Bytes = (size_t)n * DDIM;
  unsigned char* qf8 = (unsigned char*)w;
  unsigned char* rf8 = (unsigned char*)(w + f8Bytes);
  float* pos     = (float*)(w + 2 * f8Bytes);
  float* row_sum = pos + n;

  prep_kernel<<<n / 4, 256, 0, stream>>>(q, r, qf8, rf8, pos, row_sum);

  dim3 grid(n / BROWS, n / (NT * BN));   // 32 x 16 = 512 blocks (2/CU)
  gemm_lse_kernel<<<grid, 256, 0, stream>>>(qf8, rf8, row_sum);

  finalize_kernel<<<1, 256, 0, stream>>>(row_sum, pos, (float*)d_out, n);
}